// Round 10
// baseline (1408.560 us; speedup 1.0000x reference)
//
#include <hip/hip_runtime.h>
#include <hip/hip_bf16.h>

// Problem dims
constexpr int cB = 8, cNQ = 300, cNK = 4096, cE = 256, cH = 8, cD = 32, cF = 2048, cL = 6;
constexpr int MT = cB * cNQ;    // 2400 rows of target stream
constexpr int MM = cB * cNK;    // 32768 rows of memory stream
constexpr int cQT = 10;         // q-tiles of 32
constexpr int cKSc = 8;         // k-split (cross)
constexpr int cKSs = 4;         // k-split (self)
constexpr float kScale = 0.17677669529663687f;   // 32^-0.5
constexpr float kE = 0.25509966355953075f;       // kScale * log2(e)
constexpr size_t pStrO = (size_t)MT * 256;
constexpr size_t pStrL = 64 * 320;

typedef __attribute__((ext_vector_type(8))) short short8_t;
typedef __attribute__((ext_vector_type(4))) short short4_t;
typedef __attribute__((ext_vector_type(4))) float float4_t;

__device__ inline short f2bf(float x) {
  __hip_bfloat16 h = __float2bfloat16(x);
  return __builtin_bit_cast(short, h);
}

// ---------------- init t (fp32 + bf16 mirror) ----------------
__global__ void init_t(const float* __restrict__ in, float* __restrict__ t,
                       __hip_bfloat16* __restrict__ tb, int n) {
  int i = blockIdx.x * 256 + threadIdx.x;
  if (i < n) { float v = in[i]; t[i] = v; tb[i] = __float2bfloat16(v); }
}
__global__ void cast_f32_bf16(const float* __restrict__ in, __hip_bfloat16* __restrict__ out, int n) {
  int i = blockIdx.x * 256 + threadIdx.x;
  if (i < n) out[i] = __float2bfloat16(in[i]);
}

// ---------------- transposed mask pack: mT[b][qt][key], bit j = mask[b][qt*32+j][key] ----
__global__ void pack_mask_T(const int* __restrict__ m, unsigned* __restrict__ mT) {
  int key = blockIdx.x * 256 + threadIdx.x;
  int qt = blockIdx.y, b = blockIdx.z;
  unsigned w = 0;
  for (int j = 0; j < 32; ++j) {
    int q = qt * 32 + j;
    unsigned bit = (q < cNQ) ? (unsigned)(m[((size_t)b * cNQ + q) * cNK + key] != 0) : 0u;
    w |= bit << j;
  }
  mT[((size_t)b * cQT + qt) * cNK + key] = w;
}

// ---------------- 64x64 MFMA GEMM ----------------
// NKS>0: A = pO (fp32 k-split partials, K must be 256); staging merges: a = sum_ks(pO)/sum_ks(pL).
// Else TA float (cvt) or bf16 (direct). W: TW. EPI 0/1(relu). OMODE 0 row / 1 K-headmajor / 2 V-T.
template<typename TA, typename TW, int EPI, int OMODE, typename TOUT, int NKS>
__global__ __launch_bounds__(256) void gemm_mfma(const TA* __restrict__ A,
                                                 const TW* __restrict__ W,
                                                 const float* __restrict__ bias,
                                                 TOUT* __restrict__ C,
                                                 int M, int N, int K,
                                                 const float* __restrict__ pL) {
  constexpr int LDSS = 72;
  __shared__ short As[64][LDSS];
  __shared__ short Ws[64][LDSS];
  int tid = threadIdx.x;
  int bm = blockIdx.x * 64, bn = blockIdx.y * 64;
  int lane = tid & 63, wave = tid >> 6;
  int m16 = lane & 15, quad = lane >> 4;
  int wm = (wave >> 1) * 32, wn = (wave & 1) * 32;

  int srow = tid >> 2;
  int kc = (tid & 3) * 16;
  bool aok = (bm + srow) < M;

  float4_t acc[2][2];
#pragma unroll
  for (int i = 0; i < 2; ++i)
#pragma unroll
    for (int j = 0; j < 2; ++j) acc[i][j] = (float4_t){0.f, 0.f, 0.f, 0.f};

  for (int k0 = 0; k0 < K; k0 += 64) {
    if constexpr (NKS > 0) {
      const float* pO = (const float*)A;
      short8_t p0 = 0, p1 = 0;
      if (aok) {
        int m = bm + srow;
        int bz = m / cNQ, qq = m - bz * cNQ;
        int h = (k0 + kc) >> 5;
        float l = 0.f;
#pragma unroll
        for (int ks = 0; ks < NKS; ++ks)
          l += pL[(size_t)ks * pStrL + (size_t)(bz * 8 + h) * 320 + qq];
        float inv = 1.f / l;
        float v[16];
#pragma unroll
        for (int c = 0; c < 4; ++c) {
          float4_t sum = {0.f, 0.f, 0.f, 0.f};
#pragma unroll
          for (int ks = 0; ks < NKS; ++ks) {
            float4_t x = *(const float4_t*)&pO[(size_t)ks * pStrO + (size_t)m * 256 + k0 + kc + c * 4];
#pragma unroll
            for (int u = 0; u < 4; ++u) sum[u] += x[u];
          }
#pragma unroll
          for (int u = 0; u < 4; ++u) v[c * 4 + u] = sum[u] * inv;
        }
#pragma unroll
        for (int u = 0; u < 8; ++u) { p0[u] = f2bf(v[u]); p1[u] = f2bf(v[8 + u]); }
      }
      *(short8_t*)&As[srow][kc] = p0;
      *(short8_t*)&As[srow][kc + 8] = p1;
    } else if constexpr (__hip_internal::is_same<TA, float>::value) {
      const float* src = A + (size_t)(bm + srow) * K + k0 + kc;
      short8_t p0, p1;
#pragma unroll
      for (int u = 0; u < 8; ++u) p0[u] = aok ? f2bf(src[u]) : (short)0;
#pragma unroll
      for (int u = 0; u < 8; ++u) p1[u] = aok ? f2bf(src[8 + u]) : (short)0;
      *(short8_t*)&As[srow][kc] = p0;
      *(short8_t*)&As[srow][kc + 8] = p1;
    } else {
      const TA* src = A + (size_t)(bm + srow) * K + k0 + kc;
      short8_t z = 0;
      *(short8_t*)&As[srow][kc] = aok ? *(const short8_t*)src : z;
      *(short8_t*)&As[srow][kc + 8] = aok ? *(const short8_t*)(src + 8) : z;
    }
    if constexpr (__hip_internal::is_same<TW, float>::value) {
      const float* src = W + (size_t)(bn + srow) * K + k0 + kc;
      short8_t p0, p1;
#pragma unroll
      for (int u = 0; u < 8; ++u) p0[u] = f2bf(src[u]);
#pragma unroll
      for (int u = 0; u < 8; ++u) p1[u] = f2bf(src[8 + u]);
      *(short8_t*)&Ws[srow][kc] = p0;
      *(short8_t*)&Ws[srow][kc + 8] = p1;
    } else {
      const TW* src = W + (size_t)(bn + srow) * K + k0 + kc;
      *(short8_t*)&Ws[srow][kc] = *(const short8_t*)src;
      *(short8_t*)&Ws[srow][kc + 8] = *(const short8_t*)(src + 8);
    }
    __syncthreads();
#pragma unroll
    for (int kk = 0; kk < 2; ++kk) {
      short8_t aF[2], bF[2];
#pragma unroll
      for (int i = 0; i < 2; ++i)
        aF[i] = *(const short8_t*)&As[wm + i * 16 + m16][kk * 32 + quad * 8];
#pragma unroll
      for (int j = 0; j < 2; ++j)
        bF[j] = *(const short8_t*)&Ws[wn + j * 16 + m16][kk * 32 + quad * 8];
#pragma unroll
      for (int i = 0; i < 2; ++i)
#pragma unroll
        for (int j = 0; j < 2; ++j)
          acc[i][j] = __builtin_amdgcn_mfma_f32_16x16x32_bf16(aF[i], bF[j], acc[i][j], 0, 0, 0);
    }
    __syncthreads();
  }

  if constexpr (OMODE == 2) {
#pragma unroll
    for (int i = 0; i < 2; ++i)
#pragma unroll
      for (int r = 0; r < 4; ++r) {
        int ml = wm + i * 16 + quad * 4 + r;
#pragma unroll
        for (int j = 0; j < 2; ++j) {
          int nl = wn + j * 16 + m16;
          Ws[nl][ml] = f2bf(acc[i][j][r] + bias[bn + nl]);
        }
      }
    __syncthreads();
    int nl = tid >> 2, mc = (tid & 3) * 16;
    if (bm + mc < M) {
      int n = bn + nl;
      __hip_bfloat16* dst = (__hip_bfloat16*)C +
          ((size_t)(n >> 5) * 32 + (n & 31)) * (size_t)M + bm + mc;
      *(short8_t*)dst = *(const short8_t*)&Ws[nl][mc];
      *(short8_t*)(dst + 8) = *(const short8_t*)&Ws[nl][mc + 8];
    }
  } else {
#pragma unroll
    for (int i = 0; i < 2; ++i) {
#pragma unroll
      for (int r = 0; r < 4; ++r) {
        int m = bm + wm + i * 16 + quad * 4 + r;
        if (m >= M) continue;
#pragma unroll
        for (int j = 0; j < 2; ++j) {
          int n = bn + wn + j * 16 + m16;
          float v = acc[i][j][r] + bias[n];
          if (EPI == 1) v = fmaxf(v, 0.f);
          if constexpr (OMODE == 1) {
            ((__hip_bfloat16*)C)[((size_t)(n >> 5) * M + m) * 32 + (n & 31)] = __float2bfloat16(v);
          } else if constexpr (__hip_internal::is_same<TOUT, float>::value) {
            C[(size_t)m * N + n] = v;
          } else {
            C[(size_t)m * N + n] = __float2bfloat16(v);
          }
        }
      }
    }
  }
}

// ---------------- 128x128 MFMA GEMM (FFN-w1) ----------------
template<typename TW, int EPI, typename TOUT>
__global__ __launch_bounds__(256) void gemm128(const __hip_bfloat16* __restrict__ A,
                                               const TW* __restrict__ W,
                                               const float* __restrict__ bias,
                                               TOUT* __restrict__ C,
                                               int M, int N, int K) {
  __shared__ short lds[2 * 128 * 72];
  auto As = (short(*)[72])lds;
  auto Ws = (short(*)[72])(lds + 128 * 72);
  int tid = threadIdx.x;
  int bm = blockIdx.x * 128, bn = blockIdx.y * 128;
  int lane = tid & 63, wave = tid >> 6;
  int n16 = lane & 15, quad = lane >> 4;
  int wm = (wave >> 1) * 64, wn = (wave & 1) * 64;
  int srow = tid >> 1, kc = (tid & 1) * 32;
  bool aok = (bm + srow) < M;

  float4_t acc[4][4];
#pragma unroll
  for (int i = 0; i < 4; ++i)
#pragma unroll
    for (int j = 0; j < 4; ++j) acc[i][j] = (float4_t){0.f, 0.f, 0.f, 0.f};

  for (int k0 = 0; k0 < K; k0 += 64) {
    {
      const __hip_bfloat16* src = A + (size_t)(bm + srow) * K + k0 + kc;
      short8_t z = 0;
#pragma unroll
      for (int u = 0; u < 4; ++u)
        *(short8_t*)&As[srow][kc + u * 8] = aok ? *(const short8_t*)(src + u * 8) : z;
    }
    if constexpr (__hip_internal::is_same<TW, float>::value) {
      const float* src = W + (size_t)(bn + srow) * K + k0 + kc;
#pragma unroll
      for (int u = 0; u < 4; ++u) {
        short8_t p;
#pragma unroll
        for (int v = 0; v < 8; ++v) p[v] = f2bf(src[u * 8 + v]);
        *(short8_t*)&Ws[srow][kc + u * 8] = p;
      }
    } else {
      const TW* src = W + (size_t)(bn + srow) * K + k0 + kc;
#pragma unroll
      for (int u = 0; u < 4; ++u)
        *(short8_t*)&Ws[srow][kc + u * 8] = *(const short8_t*)(src + u * 8);
    }
    __syncthreads();
#pragma unroll
    for (int kk = 0; kk < 2; ++kk) {
      short8_t aF[4], bF[4];
#pragma unroll
      for (int i = 0; i < 4; ++i)
        aF[i] = *(const short8_t*)&As[wm + i * 16 + n16][kk * 32 + quad * 8];
#pragma unroll
      for (int j = 0; j < 4; ++j)
        bF[j] = *(const short8_t*)&Ws[wn + j * 16 + n16][kk * 32 + quad * 8];
#pragma unroll
      for (int i = 0; i < 4; ++i)
#pragma unroll
        for (int j = 0; j < 4; ++j)
          acc[i][j] = __builtin_amdgcn_mfma_f32_16x16x32_bf16(aF[i], bF[j], acc[i][j], 0, 0, 0);
    }
    __syncthreads();
  }

#pragma unroll
  for (int i = 0; i < 4; ++i) {
#pragma unroll
    for (int r = 0; r < 4; ++r) {
      int m = bm + wm + i * 16 + quad * 4 + r;
      if (m >= M) continue;
#pragma unroll
      for (int j = 0; j < 4; ++j) {
        int n = bn + wn + j * 16 + n16;
        float v = acc[i][j][r] + bias[n];
        if (EPI == 1) v = fmaxf(v, 0.f);
        if constexpr (__hip_internal::is_same<TOUT, float>::value)
          C[(size_t)m * N + n] = v;
        else
          C[(size_t)m * N + n] = __float2bfloat16(v);
      }
    }
  }
}

// ---------------- fused K+V projection (128-tile), blockIdx.z: 0=K headmajor, 1=V transposed ----
template<typename TA, typename TW>
__global__ __launch_bounds__(256) void gemm_kv(const TA* __restrict__ A,
                                               const TW* __restrict__ Wk, const TW* __restrict__ Wv,
                                               const float* __restrict__ bk, const float* __restrict__ bv,
                                               __hip_bfloat16* __restrict__ Ck,
                                               __hip_bfloat16* __restrict__ Cv,
                                               int M, int K) {
  __shared__ short lds[2 * 128 * 72];
  auto As = (short(*)[72])lds;
  auto Ws = (short(*)[72])(lds + 128 * 72);
  bool isV = blockIdx.z == 1;
  const TW* W = isV ? Wv : Wk;
  const float* bias = isV ? bv : bk;
  int tid = threadIdx.x;
  int bm = blockIdx.x * 128, bn = blockIdx.y * 128;
  int lane = tid & 63, wave = tid >> 6;
  int n16 = lane & 15, quad = lane >> 4;
  int wm = (wave >> 1) * 64, wn = (wave & 1) * 64;
  int srow = tid >> 1, kc = (tid & 1) * 32;
  bool aok = (bm + srow) < M;

  float4_t acc[4][4];
#pragma unroll
  for (int i = 0; i < 4; ++i)
#pragma unroll
    for (int j = 0; j < 4; ++j) acc[i][j] = (float4_t){0.f, 0.f, 0.f, 0.f};

  for (int k0 = 0; k0 < K; k0 += 64) {
    if constexpr (__hip_internal::is_same<TA, float>::value) {
      const float* src = A + (size_t)(bm + srow) * K + k0 + kc;
#pragma unroll
      for (int u = 0; u < 4; ++u) {
        short8_t p;
#pragma unroll
        for (int v = 0; v < 8; ++v) p[v] = aok ? f2bf(src[u * 8 + v]) : (short)0;
        *(short8_t*)&As[srow][kc + u * 8] = p;
      }
    } else {
      const TA* src = A + (size_t)(bm + srow) * K + k0 + kc;
      short8_t z = 0;
#pragma unroll
      for (int u = 0; u < 4; ++u)
        *(short8_t*)&As[srow][kc + u * 8] = aok ? *(const short8_t*)(src + u * 8) : z;
    }
    if constexpr (__hip_internal::is_same<TW, float>::value) {
      const float* src = W + (size_t)(bn + srow) * K + k0 + kc;
#pragma unroll
      for (int u = 0; u < 4; ++u) {
        short8_t p;
#pragma unroll
        for (int v = 0; v < 8; ++v) p[v] = f2bf(src[u * 8 + v]);
        *(short8_t*)&Ws[srow][kc + u * 8] = p;
      }
    } else {
      const TW* src = W + (size_t)(bn + srow) * K + k0 + kc;
#pragma unroll
      for (int u = 0; u < 4; ++u)
        *(short8_t*)&Ws[srow][kc + u * 8] = *(const short8_t*)(src + u * 8);
    }
    __syncthreads();
#pragma unroll
    for (int kk = 0; kk < 2; ++kk) {
      short8_t aF[4], bF[4];
#pragma unroll
      for (int i = 0; i < 4; ++i)
        aF[i] = *(const short8_t*)&As[wm + i * 16 + n16][kk * 32 + quad * 8];
#pragma unroll
      for (int j = 0; j < 4; ++j)
        bF[j] = *(const short8_t*)&Ws[wn + j * 16 + n16][kk * 32 + quad * 8];
#pragma unroll
      for (int i = 0; i < 4; ++i)
#pragma unroll
        for (int j = 0; j < 4; ++j)
          acc[i][j] = __builtin_amdgcn_mfma_f32_16x16x32_bf16(aF[i], bF[j], acc[i][j], 0, 0, 0);
    }
    __syncthreads();
  }

  if (isV) {
    auto TT = (short(*)[128])lds;
#pragma unroll
    for (int i = 0; i < 4; ++i)
#pragma unroll
      for (int r = 0; r < 4; ++r) {
        int ml = wm + i * 16 + quad * 4 + r;
#pragma unroll
        for (int j = 0; j < 4; ++j) {
          int nl = wn + j * 16 + n16;
          TT[nl][ml] = f2bf(acc[i][j][r] + bias[bn + nl]);
        }
      }
    __syncthreads();
    int nl = tid >> 1, mh = (tid & 1) * 64;
    int n = bn + nl;
    __hip_bfloat16* dst = Cv + ((size_t)(n >> 5) * 32 + (n & 31)) * (size_t)M + bm + mh;
#pragma unroll
    for (int ch = 0; ch < 8; ++ch) {
      if (bm + mh + ch * 8 < M)
        *(short8_t*)(dst + ch * 8) = *(const short8_t*)&TT[nl][mh + ch * 8];
    }
  } else {
#pragma unroll
    for (int i = 0; i < 4; ++i) {
#pragma unroll
      for (int r = 0; r < 4; ++r) {
        int m = bm + wm + i * 16 + quad * 4 + r;
        if (m >= M) continue;
#pragma unroll
        for (int j = 0; j < 4; ++j) {
          int n = bn + wn + j * 16 + n16;
          float v = acc[i][j][r] + bias[n];
          Ck[((size_t)(n >> 5) * M + m) * 32 + (n & 31)] = __float2bfloat16(v);
        }
      }
    }
  }
}

// ---------------- flash attention, single wave per (hb, q-tile32, k-chunk) ----------------
// Prefetched K/V/mask; no-max softmax via exp2; bf16 pair pack via bit trick.
template<typename TQ, bool MASKED>
__global__ __launch_bounds__(64, 4) void attn_flash(
    const TQ* __restrict__ qb, size_t strQb, size_t strQh, int qRowStr,
    const __hip_bfloat16* __restrict__ kb, size_t strKb, size_t strKh, int kRowStr,
    const __hip_bfloat16* __restrict__ vt, size_t strVb, size_t strVh, size_t strVd,
    const unsigned* __restrict__ mT, size_t strMb,
    float* __restrict__ pO, float* __restrict__ pL,
    int nq, int nk, int kChunk) {
  int hb = blockIdx.x;
  int h = hb & 7, bz = hb >> 3;
  int qt = blockIdx.y, ks = blockIdx.z;
  int qbase = qt * 32;

  const TQ* q = qb + (size_t)bz * strQb + (size_t)h * strQh;
  const __hip_bfloat16* K = kb + (size_t)bz * strKb + (size_t)h * strKh;
  const __hip_bfloat16* V = vt + (size_t)bz * strVb + (size_t)h * strVh;
  const unsigned* mrow = MASKED ? (mT + (size_t)bz * strMb + (size_t)qt * cNK) : nullptr;

  int lane = threadIdx.x;
  int n16 = lane & 15, quad = lane >> 4;

  __shared__ short sP[32][40];

  short8_t qf[2];
#pragma unroll
  for (int qi = 0; qi < 2; ++qi) {
    qf[qi] = 0;
    int qr = qbase + qi * 16 + n16;
    if (qr < nq) {
      const TQ* qp = q + (size_t)qr * qRowStr + quad * 8;
      if constexpr (__hip_internal::is_same<TQ, float>::value) {
#pragma unroll
        for (int j = 0; j < 8; ++j) qf[qi][j] = f2bf(qp[j]);
      } else {
        qf[qi] = *(const short8_t*)qp;
      }
    }
  }
  short8_t ones;
#pragma unroll
  for (int j = 0; j < 8; ++j) ones[j] = f2bf(1.0f);

  float4_t accO[2][2], accL[2];
#pragma unroll
  for (int qi = 0; qi < 2; ++qi) {
    accL[qi] = (float4_t){0.f, 0.f, 0.f, 0.f};
#pragma unroll
    for (int di = 0; di < 2; ++di) accO[qi][di] = (float4_t){0.f, 0.f, 0.f, 0.f};
  }
  float4_t zero4 = {0.f, 0.f, 0.f, 0.f};

  const __hip_bfloat16* Vb0 = V + (size_t)n16 * strVd;
  const __hip_bfloat16* Vb1 = V + (size_t)(16 + n16) * strVd;

  int kbeg = ks * kChunk;
  int kend = kbeg + kChunk;
  int nkAl = (nk + 31) & ~31;
  if (kend > nkAl) kend = nkAl;

  short8_t kfA = 0, kfB = 0, vfA = 0, vfB = 0;
  unsigned mwA = ~0u, mwB = ~0u;
  if (kbeg < kend) {
    int k0i = kbeg + 2 * n16;
    kfA = *(const short8_t*)(K + (size_t)k0i * kRowStr + quad * 8);
    kfB = *(const short8_t*)(K + (size_t)(k0i + 1) * kRowStr + quad * 8);
    vfA = *(const short8_t*)(Vb0 + kbeg + quad * 8);
    vfB = *(const short8_t*)(Vb1 + kbeg + quad * 8);
    if (MASKED) { mwA = mrow[k0i]; mwB = mrow[k0i + 1]; }
  }

  for (int koff = kbeg; koff < kend; koff += 32) {
    // ---- prefetch next step ----
    short8_t kfA2 = 0, kfB2 = 0, vfA2 = 0, vfB2 = 0;
    unsigned mwA2 = ~0u, mwB2 = ~0u;
    int kn = koff + 32;
    if (kn < kend) {
      int k1i = kn + 2 * n16;
      kfA2 = *(const short8_t*)(K + (size_t)k1i * kRowStr + quad * 8);
      kfB2 = *(const short8_t*)(K + (size_t)(k1i + 1) * kRowStr + quad * 8);
      vfA2 = *(const short8_t*)(Vb0 + kn + quad * 8);
      vfB2 = *(const short8_t*)(Vb1 + kn + quad * 8);
      if (MASKED) { mwA2 = mrow[k1i]; mwB2 = mrow[k1i + 1]; }
    }
    // ---- current step ----
    int k0i = koff + 2 * n16;
    bool in0 = k0i < nk, in1 = (k0i + 1) < nk;
    float4_t s00 = __builtin_amdgcn_mfma_f32_16x16x32_bf16(qf[0], kfA, zero4, 0, 0, 0);
    float4_t s01 = __builtin_amdgcn_mfma_f32_16x16x32_bf16(qf[0], kfB, zero4, 0, 0, 0);
    float4_t s10 = __builtin_amdgcn_mfma_f32_16x16x32_bf16(qf[1], kfA, zero4, 0, 0, 0);
    float4_t s11 = __builtin_amdgcn_mfma_f32_16x16x32_bf16(qf[1], kfB, zero4, 0, 0, 0);
#pragma unroll
    for (int qi = 0; qi < 2; ++qi) {
      const float4_t& sa = qi ? s10 : s00;
      const float4_t& sb = qi ? s11 : s01;
#pragma unroll
      for (int r = 0; r < 4; ++r) {
        int row = qi * 16 + quad * 4 + r;
        bool ok0 = in0, ok1 = in1;
        if (MASKED) {
          ok0 = ok0 && ((mwA >> row) & 1u);
          ok1 = ok1 && ((mwB >> row) & 1u);
        }
        float p0 = ok0 ? exp2f(sa[r] * kE) : 0.f;
        float p1 = ok1 ? exp2f(sb[r] * kE) : 0.f;
        unsigned u0 = __builtin_bit_cast(unsigned, p0);
        unsigned u1 = __builtin_bit_cast(unsigned, p1);
        unsigned pw = ((u0 + 0x8000u) >> 16) | ((u1 + 0x8000u) & 0xFFFF0000u);
        *(unsigned*)&sP[row][2 * n16] = pw;
      }
    }
#pragma unroll
    for (int qi = 0; qi < 2; ++qi) {
      short8_t pf = *(const short8_t*)&sP[qi * 16 + n16][quad * 8];
      accO[qi][0] = __builtin_amdgcn_mfma_f32_16x16x32_bf16(pf, vfA, accO[qi][0], 0, 0, 0);
      accO[qi][1] = __builtin_amdgcn_mfma_f32_16x16x32_bf16(pf, vfB, accO[qi][1], 0, 0, 0);
      accL[qi]    = __builtin_amdgcn_mfma_f32_16x16x32_bf16(pf, ones, accL[qi], 0, 0, 0);
    }
    kfA = kfA2; kfB = kfB2; vfA = vfA2; vfB = vfB2; mwA = mwA2; mwB = mwB2;
  }

  size_t oBase = (size_t)ks * pStrO + (size_t)(bz * cNQ) * 256 + h * 32;
  size_t lBase = (size_t)ks * pStrL + (size_t)hb * 320;
#pragma unroll
  for (int qi = 0; qi < 2; ++qi) {
#pragma unroll
    for (int r = 0; r < 4; ++r) {
      int row = qi * 16 + quad * 4 + r;
      if (qbase + row >= nq) continue;
#pragma unroll
      for (int di = 0; di < 2; ++di)
        pO[oBase + (size_t)(qbase + row) * 256 + di * 16 + n16] = accO[qi][di][r];
      if (n16 == 0) pL[lBase + qbase + row] = accL[qi][r];
    }
  }
}

// ---------------- residual + LayerNorm (fp32 t + bf16 mirror) ----------------
__global__ __launch_bounds__(64) void add_ln_k(float* __restrict__ t,
                                               __hip_bfloat16* __restrict__ tb,
                                               const float* __restrict__ delta,
                                               const float* __restrict__ g,
                                               const float* __restrict__ bb) {
  int r = blockIdx.x, lane = threadIdx.x;
  size_t base = (size_t)r * cE + lane * 4;
  float x[4];
  float s = 0.f;
#pragma unroll
  for (int i = 0; i < 4; ++i) { x[i] = t[base + i] + delta[base + i]; s += x[i]; }
  for (int off = 32; off; off >>= 1) s += __shfl_xor(s, off);
  float mean = s * (1.f / cE);
  float v = 0.f;
#pragma unroll
  for (int i = 0; i < 4; ++i) { float dd = x[i] - mean; v += dd * dd; }
  for (int off = 32; off; off >>= 1) v += __shfl_xor(v, off);
  float rstd = rsqrtf(v * (1.f / cE) + 1e-5f);
  float y[4];
#pragma unroll
  for (int i = 0; i < 4; ++i) {
    y[i] = (x[i] - mean) * rstd * g[lane * 4 + i] + bb[lane * 4 + i];
    t[base + i] = y[i];
  }
  short4_t pb = {f2bf(y[0]), f2bf(y[1]), f2bf(y[2]), f2bf(y[3])};
  *(short4_t*)&tb[base] = pb;
}

// ---------------- final LayerNorm -> fp32 out ----------------
__global__ __launch_bounds__(64) void final_ln_k(const float* __restrict__ t,
                                                 const float* __restrict__ g,
                                                 const float* __restrict__ bb,
                                                 float* __restrict__ out) {
  int r = blockIdx.x, lane = threadIdx.x;
  size_t base = (size_t)r * cE + lane * 4;
  float x[4];
  float s = 0.f;
#pragma unroll
  for (int i = 0; i < 4; ++i) { x[i] = t[base + i]; s += x[i]; }
  for (int off = 32; off; off >>= 1) s += __shfl_xor(s, off);
  float mean = s * (1.f / cE);
  float v = 0.f;
#pragma unroll
  for (int i = 0; i < 4; ++i) { float dd = x[i] - mean; v += dd * dd; }
  for (int off = 32; off; off >>= 1) v += __shfl_xor(v, off);
  float rstd = rsqrtf(v * (1.f / cE) + 1e-5f);
#pragma unroll
  for (int i = 0; i < 4; ++i)
    out[base + i] = (x[i] - mean) * rstd * g[lane * 4 + i] + bb[lane * 4 + i];
}

// ---------------- pipeline ----------------
struct Bufs {
  float *t, *s1, *s2, *pO, *pL;
  __hip_bfloat16 *tb, *big2, *vtq, *qbf, *ffnh, *kbuf, *vtb, *membf;
  unsigned* mTr;
  const float* memory;
  bool fullKV, precast;
};

template<typename TW>
static void run_layers(const TW* const* wt, const float* const* bs,
                       const float* ln1g, const float* ln1b,
                       const float* ln2g, const float* ln2b,
                       const float* ln3g, const float* ln3b,
                       Bufs B, hipStream_t stream) {
  for (int l = 0; l < cL; ++l) {
    const TW* wqkv = wt[0] + (size_t)l * 3 * cE * cE;  const float* bqkv = bs[0] + (size_t)l * 3 * cE;
    const TW* wo   = wt[1] + (size_t)l * cE * cE;      const float* bo   = bs[1] + (size_t)l * cE;
    const TW* wq   = wt[2] + (size_t)l * cE * cE;      const float* bq   = bs[2] + (size_t)l * cE;
    const TW* wk   = wt[3] + (size_t)l * cE * cE;      const float* bk   = bs[3] + (size_t)l * cE;
    const TW* wv   = wt[4] + (size_t)l * cE * cE;      const float* bv   = bs[4] + (size_t)l * cE;
    const TW* wco  = wt[5] + (size_t)l * cE * cE;      const float* bco  = bs[5] + (size_t)l * cE;
    const TW* w1   = wt[6] + (size_t)l * cF * cE;      const float* b1   = bs[6] + (size_t)l * cF;
    const TW* w2   = wt[7] + (size_t)l * cE * cF;      const float* b2   = bs[7] + (size_t)l * cE;

    // 1) self Q|K -> big2 (bf16, stride 512)
    gemm_mfma<__hip_bfloat16, TW, 0, 0, __hip_bfloat16, 0><<<dim3(38, 8), 256, 0, stream>>>(
        B.tb, wqkv, bqkv, B.big2, MT, 512, cE, nullptr);
    // 2) self V^T -> vtq [h][dim][2400]
    gemm_mfma<__hip_bfloat16, TW, 0, 2, __hip_bfloat16, 0><<<dim3(38, 4), 256, 0, stream>>>(
        B.tb, wqkv + (size_t)512 * cE, bqkv + 512, B.vtq, MT, cE, cE, nullptr);
    // 3) self flash (k-split 4, chunks of 96)
    attn_flash<__hip_bfloat16, false><<<dim3(64, cQT, cKSs), 64, 0, stream>>>(
        B.big2, (size_t)cNQ * 512, 32, 512,
        B.big2 + 256, (size_t)cNQ * 512, 32, 512,
        B.vtq, 300, (size_t)cD * MT, MT,
        nullptr, 0,
        B.pO, B.pL, cNQ, cNQ, 96);
    // 4) sa out proj (A = merged partials) -> s2 fp32
    gemm_mfma<float, TW, 0, 0, float, cKSs><<<dim3(38, 4), 256, 0, stream>>>(
        B.pO, wo, bo, B.s2, MT, cE, cE, B.pL);
    add_ln_k<<<MT, 64, 0, stream>>>(B.t, B.tb, B.s2, ln1g + (size_t)l * cE, ln1b + (size_t)l * cE);
    // 5) q proj -> qbf
    gemm_mfma<__hip_bfloat16, TW, 0, 0, __hip_bfloat16, 0><<<dim3(38, 4), 256, 0, stream>>>(
        B.tb, wq, bq, B.qbf, MT, cE, cE, nullptr);
    // 6) K/V projections + cross flash
    if (B.fullKV) {
      if (B.precast)
        gemm_kv<__hip_bfloat16, TW><<<dim3(256, 2, 2), 256, 0, stream>>>(
            B.membf, wk, wv, bk, bv, B.kbuf, B.vtb, MM, cE);
      else
        gemm_kv<float, TW><<<dim3(256, 2, 2), 256, 0, stream>>>(
            B.memory, wk, wv, bk, bv, B.kbuf, B.vtb, MM, cE);
      attn_flash<__hip_bfloat16, true><<<dim3(64, cQT, cKSc), 64, 0, stream>>>(
          B.qbf, (size_t)cNQ * cE, 32, cE,
          B.kbuf, (size_t)cNK * cD, (size_t)MM * cD, cD,
          B.vtb, (size_t)cNK, (size_t)cD * MM, MM,
          B.mTr, (size_t)cQT * cNK,
          B.pO, B.pL, cNQ, cNK, 512);
    } else {
      for (int b = 0; b < cB; ++b) {
        const float* memb = B.memory + (size_t)b * cNK * cE;
        gemm_mfma<float, TW, 0, 1, __hip_bfloat16, 0><<<dim3(64, 4), 256, 0, stream>>>(
            memb, wk, bk, B.kbuf, cNK, cE, cE, nullptr);
        gemm_mfma<float, TW, 0, 2, __hip_bfloat16, 0><<<dim3(64, 4), 256, 0, stream>>>(
            memb, wv, bv, B.vtb, cNK, cE, cE, nullptr);
        attn_flash<__hip_bfloat16, true><<<dim3(8, cQT, cKSc), 64, 0, stream>>>(
            B.qbf + (size_t)b * cNQ * cE, 0, 32, cE,
            B.kbuf, 0, (size_t)cNK * cD, cD,
            B.vtb, 0, (size_t)cD * cNK, cNK,
            B.mTr + (size_t)b * cQT * cNK, 0,
            B.pO + (size_t)b * cNQ * 256, B.pL + (size_t)b * 8 * 320,
            cNQ, cNK, 512);
      }
    }
    // 7) ca out proj (A = merged partials, 8-way) -> s1 fp32
    gemm_mfma<float, TW, 0, 0, float, cKSc><<<dim3(38, 4), 256, 0, stream>>>(
        B.pO, wco, bco, B.s1, MT, cE, cE, B.pL);
    add_ln_k<<<MT, 64, 0, stream>>>(B.t, B.tb, B.s1, ln2g + (size_t)l * cE, ln2b + (size_t)l * cE);
    // 8) FFN
    gemm128<TW, 1, __hip_bfloat16><<<dim3(19, 16), 256, 0, stream>>>(
        B.tb, w1, b1, B.ffnh, MT, cF, cE);
    gemm_mfma<__hip_bfloat16, TW, 0, 0, float, 0><<<dim3(38, 4), 256, 0, stream>>>(
        B.ffnh, w2, b2, B.s1, MT, cE, cF, nullptr);
    add_ln_k<<<MT, 64, 0, stream>>>(B.t, B.tb, B.s1, ln3g + (size_t)l * cE, ln3b + (size_t)l * cE);
  }
}

extern "C" void kernel_launch(void* const* d_in, const int* in_sizes, int n_in,
                              void* d_out, int out_size, void* d_ws, size_t ws_size,
                              hipStream_t stream) {
  (void)in_sizes; (void)n_in; (void)out_size;
  const float* tgt    = (const float*)d_in[0];
  const float* memory = (const float*)d_in[1];
  const int*   gmask  = (const int*)d_in[2];
  const float* w_in[8]  = {(const float*)d_in[3], (const float*)d_in[5], (const float*)d_in[7],
                           (const float*)d_in[9], (const float*)d_in[11], (const float*)d_in[13],
                           (const float*)d_in[15], (const float*)d_in[17]};
  const float* b_in[8]  = {(const float*)d_in[4], (const float*)d_in[6], (const float*)d_in[8],
                           (const float*)d_in[10], (const float*)d_in[12], (const float*)d_in[14],
                           (const float*)d_in[16], (const float*)d_in[18]};
  const size_t w_sz[8]  = {(size_t)cL*3*cE*cE, (size_t)cL*cE*cE, (size_t)cL*cE*cE,
                           (size_t)cL*cE*cE, (size_t)cL*cE*cE, (size_t)cL*cE*cE,
                           (size_t)cL*cF*cE, (size_t)cL*cE*cF};
  const float* ln1g = (const float*)d_in[19], *ln1b = (const float*)d_in[20];
  const float* ln2g = (const float*)d_in[21], *ln2b = (const float*)d_in[22];
  const float* ln3g = (const float*)d_in[23], *ln3b = (const float*)d_in[24];
  const float* lnfg = (const float*)d_in[25], *lnfb = (const float*)d_in[26];

  // ---- workspace allocator (256B aligned), ordered by value ----
  char* wp = (char*)d_ws;
  auto alloc = [&](size_t bytes) { void* p = wp; wp += (bytes + 255) & ~(size_t)255; return p; };

  Bufs B;
  B.memory = memory;
  B.t  = (float*)alloc((size_t)MT * cE * 4);
  B.s1 = (float*)alloc((size_t)MT * cE * 4);
  B.s2 = (float*)alloc((size_t)MT * cE * 4);
  B.tb = (__hip_bfloat16*)alloc((size_t)MT * cE * 2);
  B.big2 = (__hip_bfloat16*)alloc((size_t)MT * 512 * 2);
  B.vtq  = (__hip_bfloat16*)alloc((size_t)cH * cD * MT * 2);
  B.mTr = (unsigned*)alloc((size_t)cB * cQT * cNK * 4);
  B.pO = (float*)alloc((size_t)cKSc * MT * 256 * 4);   // 19.7 MB
  B.pL = (float*)alloc((size_t)cKSc * 64 * 320 * 4);
  B.qbf = (__hip_bfloat16*)B.s1;                        // alias
  B.ffnh = (__hip_bfloat16*)B.pO;                       // alias (pO free during FFN)

  size_t kvFull = (size_t)cH * MM * cD * 2;             // 16.78 MB each
  size_t used = (size_t)(wp - (char*)d_ws);
  B.fullKV = ws_size >= used + 2 * kvFull;
  if (B.fullKV) {
    B.kbuf = (__hip_bfloat16*)alloc(kvFull);
    B.vtb  = (__hip_bfloat16*)alloc(kvFull);
  } else {
    B.kbuf = (__hip_bfloat16*)alloc((size_t)cH * cNK * cD * 2);
    B.vtb  = (__hip_bfloat16*)alloc((size_t)cH * cNK * cD * 2);
  }
  size_t memBytes = (size_t)MM * cE * 2;
  used = (size_t)(wp - (char*)d_ws);
  B.precast = B.fullKV && (ws_size >= used + memBytes);
  B.membf = B.precast ? (__hip_bfloat16*)alloc(memBytes) : nullptr;

  size_t wbfTotal = 0;
  for (int i = 0; i < 8; ++i) wbfTotal += ((w_sz[i] * 2 + 255) & ~(size_t)255);
  used = (size_t)(wp - (char*)d_ws);
  bool wPre = ws_size >= used + wbfTotal;
  __hip_bfloat16* wbf[8] = {};
  if (wPre)
    for (int i = 0; i < 8; ++i) wbf[i] = (__hip_bfloat16*)alloc(w_sz[i] * 2);

  // ---- one-time prep ----
  init_t<<<(MT * cE + 255) / 256, 256, 0, stream>>>(tgt, B.t, B.tb, MT * cE);
  pack_mask_T<<<dim3(cNK / 256, cQT, cB), 256, 0, stream>>>(gmask, B.mTr);
  if (B.precast)
    cast_f32_bf16<<<(MM * cE + 255) / 256, 256, 0, stream>>>(memory, B.membf, MM * cE);
  if (wPre)
    for (int i = 0; i < 8; ++i)
      cast_f32_bf16<<<(int)((w_sz[i] + 255) / 256), 256, 0, stream>>>(w_in[i], wbf[i], (int)w_sz[i]);

  if (wPre) {
    const __hip_bfloat16* wt[8];
    for (int i = 0; i < 8; ++i) wt[i] = wbf[i];
    run_layers<__hip_bfloat16>(wt, b_in, ln1g, ln1b, ln2g, ln2b, ln3g, ln3b, B, stream);
  } else {
    run_layers<float>(w_in, b_in, ln1g, ln1b, ln2g, ln2b, ln3g, ln3b, B, stream);
  }

  final_ln_k<<<MT, 64, 0, stream>>>(B.t, lnfg, lnfb, (float*)d_out);
}